// Round 8
// baseline (1260.499 us; speedup 1.0000x reference)
//
#include <hip/hip_runtime.h>
#include <hip/hip_fp16.h>

// Wavefront-pipelined 20-layer ReLU RNN for MI355X — round 8.
// Keeps round 7's winning config (512 thr = 2 waves/SIMD, N=32/wave, superstep
// S=4, row-major ring, lag-1 export). Trims the three exposed serializations:
//  1. j3 barrier removed: step j only reads bufX[j], so unscrambling
//     pf[0..2] -> bufX[0..2] during j3's body is race-free; bufX[3]'s write
//     is carried in regs (pfc) to the next superstep's j0 body.
//  2. pf loads issued at j0 (3-step latency window). tid64 deep-poll target
//     s+3; consumed-counter publish lagged one superstep (cons=s at j0(s)) so
//     in-flight jj=3 loads never race a producer overwrite.
//  3. acc chains split 2x16 -> 4x8 (X-half / h-half separate, merged once):
//     4 independent MFMA dep streams per wave, 8 per SIMD.

#define B_    128
#define T_    784
#define H_    256
#define L_    20
#define C_    10
#define G_    8      // batch slices
#define BM_   16     // batch rows per block
#define S_    4      // timesteps per superstep / ring slot
#define NS_   196    // T_/S_
#define SW_   280    // LDS row stride in halves (140 dwords = 12 mod 32)
#define RQWS_ 4096   // u64 words per ring slot (4 x 16 x 256 halves = 32KB)
#define TPB_  512

typedef _Float16 v8h __attribute__((ext_vector_type(8)));
typedef float    v4f __attribute__((ext_vector_type(4)));
typedef unsigned long long u64;

__global__ __launch_bounds__(TPB_, 1)
void rnn_wavefront(const float* __restrict__ x,
                   const float* __restrict__ W_ih0,
                   const float* __restrict__ b_ih0,
                   const float* __restrict__ W_ih,
                   const float* __restrict__ b_ih,
                   const float* __restrict__ W_hh,
                   const float* __restrict__ b_hh,
                   const float* __restrict__ W_fc,
                   const float* __restrict__ b_fc,
                   float* __restrict__ out,
                   unsigned* __restrict__ prod,    // [L_][G_] supersteps complete
                   unsigned* __restrict__ cons,    // [L_][G_] supersteps consumed
                   u64* __restrict__ ring,         // [L_][G_][R][RQWS_]
                   int rmask)                      // R-1, R power of two
{
    const int l    = blockIdx.x >> 3;
    const int g    = blockIdx.x & 7;
    const int tid  = threadIdx.x;
    const int lane = tid & 63;
    const int wave = tid >> 6;          // 0..7
    const int quad = lane >> 4;
    const int s16  = lane & 15;
    const int nbase = wave * 32;        // each wave owns 32 output columns
    const int m_e  = tid >> 5;          // export/pf row (0..15)
    const int n_e  = (tid & 31) * 8;    // export/pf col base (0..248)

    __shared__ __align__(16) _Float16 bufX[S_][BM_][SW_];  // staged input slot
    __shared__ __align__(16) _Float16 lH[2][BM_][SW_];     // own h, ping-pong

    for (int i = tid; i < 2 * BM_ * SW_; i += TPB_) (&lH[0][0][0])[i] = (_Float16)0.f;

    // ---- weight B-fragments: lane holds B[k=quad*8+i][n=lane&15] ----
    v8h wf[16][2];
#pragma unroll
    for (int kt = 0; kt < 16; ++kt) {
        const int k0 = kt * 32 + quad * 8;
#pragma unroll
        for (int nt = 0; nt < 2; ++nt) {
            const int j = nbase + nt * 16 + s16;
            v8h w;
            if (kt < 8) {
                if (l == 0) {
#pragma unroll
                    for (int i = 0; i < 8; ++i) w[i] = (_Float16)0.f;
                } else {
                    const float* src = &W_ih[(((size_t)(l - 1) * H_) + j) * H_ + k0];
#pragma unroll
                    for (int i = 0; i < 8; ++i) w[i] = (_Float16)src[i];
                }
            } else {
                const float* src = &W_hh[(((size_t)l * H_) + j) * H_ + (k0 - 256)];
#pragma unroll
                for (int i = 0; i < 8; ++i) w[i] = (_Float16)src[i];
            }
            wf[kt][nt] = w;
        }
    }

    float bias[2], w0v[2];
#pragma unroll
    for (int nt = 0; nt < 2; ++nt) {
        const int j = nbase + nt * 16 + s16;
        bias[nt] = b_hh[l * H_ + j] + ((l == 0) ? b_ih0[j] : b_ih[(l - 1) * H_ + j]);
        w0v[nt]  = (l == 0) ? W_ih0[j] : 0.f;
    }

    unsigned* upprod = prod + ((l > 0 ? l - 1 : 0) * G_ + g);
    unsigned* myprod = prod + (l * G_ + g);
    unsigned* mycons = cons + (l * G_ + g);
    unsigned* dncons = cons + (((l < L_ - 1) ? l + 1 : l) * G_ + g);
    const unsigned R = (unsigned)rmask + 1u;
    u64* myring = ring + ((size_t)(l * G_ + g) * (size_t)R) * RQWS_;
    u64* upring = ring + ((size_t)((l > 0 ? l - 1 : 0) * G_ + g) * (size_t)R) * RQWS_;

    unsigned pSeen = 0, cSeen = 0;         // tid64 / tid128 private
    const size_t eidx = (size_t)m_e * 64 + (size_t)(tid & 31) * 2;  // u64 idx in slot

    // ---- prologue (l>0): wait prod>=2 (slot 0 + slot 1 for s=0's j0-pf),
    // stage slot 0 into bufX (row-major) ----
    if (l > 0) {
        if (tid == 64) {
            while (pSeen < 2u) {
                pSeen = __hip_atomic_load(upprod, __ATOMIC_RELAXED,
                                          __HIP_MEMORY_SCOPE_AGENT);
                if (pSeen < 2u) __builtin_amdgcn_s_sleep(2);
            }
        }
        __syncthreads();
#pragma unroll
        for (int jj = 0; jj < S_; ++jj) {
            u64 v0 = __hip_atomic_load(upring + (size_t)jj * 1024 + eidx,
                                       __ATOMIC_RELAXED, __HIP_MEMORY_SCOPE_AGENT);
            u64 v1 = __hip_atomic_load(upring + (size_t)jj * 1024 + eidx + 1,
                                       __ATOMIC_RELAXED, __HIP_MEMORY_SCOPE_AGENT);
            *(u64*)&bufX[jj][m_e][n_e]     = v0;
            *(u64*)&bufX[jj][m_e][n_e + 4] = v1;
        }
    }

    u64 pfc0 = 0, pfc1 = 0;   // carried jj=3 prefetch (written at next j0)

    for (int s = 0; s < NS_; ++s) {
        const bool pfOK = (l > 0) && (s + 1 < NS_);
        u64 pfv[S_][2];

#pragma unroll
        for (int j = 0; j < S_; ++j) {
            const int t = S_ * s + j;
            __syncthreads();   // step barrier

            if (j == 0) {
                // carried unscramble: bufX[3] of THIS superstep's slot
                if (l > 0 && s > 0) {
                    *(u64*)&bufX[3][m_e][n_e]     = pfc0;
                    *(u64*)&bufX[3][m_e][n_e + 4] = pfc1;
                }
                if (tid == 0) {
                    if (l > 0 && s > 0)
                        __hip_atomic_store(mycons, (unsigned)s, __ATOMIC_RELAXED,
                                           __HIP_MEMORY_SCOPE_AGENT); // slots < s free
                    if (l < L_ - 1 && s >= 1)
                        __hip_atomic_store(myprod, (unsigned)s, __ATOMIC_RELAXED,
                                           __HIP_MEMORY_SCOPE_AGENT); // slots < s done
                }
                if (tid == 64 && l > 0 && s <= NS_ - 3) {  // guards pf at j0(s+1)
                    const unsigned tgt = (unsigned)(s + 3);
                    while (pSeen < tgt) {
                        pSeen = __hip_atomic_load(upprod, __ATOMIC_RELAXED,
                                                  __HIP_MEMORY_SCOPE_AGENT);
                        if (pSeen < tgt) __builtin_amdgcn_s_sleep(2);
                    }
                }
                if (tid == 128 && l < L_ - 1 && s >= (int)R) {  // guards exports
                    const unsigned tgt = (unsigned)(s - (int)R + 1);
                    while (cSeen < tgt) {
                        cSeen = __hip_atomic_load(dncons, __ATOMIC_RELAXED,
                                                  __HIP_MEMORY_SCOPE_AGENT);
                        if (cSeen < tgt) __builtin_amdgcn_s_sleep(2);
                    }
                }
                if (pfOK) {   // prefetch slot s+1 -> regs (guarantee from s-1 poll)
                    const u64* base = upring + (size_t)((s + 1) & rmask) * RQWS_;
#pragma unroll
                    for (int jj = 0; jj < S_; ++jj) {
                        pfv[jj][0] = __hip_atomic_load(base + (size_t)jj * 1024 + eidx,
                                                       __ATOMIC_RELAXED,
                                                       __HIP_MEMORY_SCOPE_AGENT);
                        pfv[jj][1] = __hip_atomic_load(base + (size_t)jj * 1024 + eidx + 1,
                                                       __ATOMIC_RELAXED,
                                                       __HIP_MEMORY_SCOPE_AGENT);
                    }
                }
            }

            // ---- export h(t-1) (lag 1 step; lH[t&1] holds h(t-1)) ----
            if (l < L_ - 1 && t > 0) {
                u64 e0 = *(const u64*)&lH[t & 1][m_e][n_e];
                u64 e1 = *(const u64*)&lH[t & 1][m_e][n_e + 4];
                u64* d = myring + (size_t)(((t - 1) >> 2) & rmask) * RQWS_
                                + (size_t)((t - 1) & 3) * 1024 + eidx;
                __hip_atomic_store(d,     e0, __ATOMIC_RELAXED, __HIP_MEMORY_SCOPE_AGENT);
                __hip_atomic_store(d + 1, e1, __ATOMIC_RELAXED, __HIP_MEMORY_SCOPE_AGENT);
            }

            // ---- MFMA: 4 independent chains of 8 (X-half, h-half per nt) ----
            v4f accA0 = (v4f){0.f, 0.f, 0.f, 0.f}, accA1 = (v4f){0.f, 0.f, 0.f, 0.f};
            v4f accB0 = (v4f){0.f, 0.f, 0.f, 0.f}, accB1 = (v4f){0.f, 0.f, 0.f, 0.f};
            if (l > 0) {
#pragma unroll
                for (int kt = 0; kt < 8; ++kt) {
                    v8h a = *(const v8h*)&bufX[j][s16][kt * 32 + quad * 8];
                    accA0 = __builtin_amdgcn_mfma_f32_16x16x32_f16(a, wf[kt][0], accA0, 0, 0, 0);
                    accA1 = __builtin_amdgcn_mfma_f32_16x16x32_f16(a, wf[kt][1], accA1, 0, 0, 0);
                }
            }
#pragma unroll
            for (int kt = 8; kt < 16; ++kt) {
                v8h a = *(const v8h*)&lH[t & 1][s16][(kt - 8) * 32 + quad * 8];
                accB0 = __builtin_amdgcn_mfma_f32_16x16x32_f16(a, wf[kt][0], accB0, 0, 0, 0);
                accB1 = __builtin_amdgcn_mfma_f32_16x16x32_f16(a, wf[kt][1], accB1, 0, 0, 0);
            }

            float xv[4];
            if (l == 0) {
#pragma unroll
                for (int r = 0; r < 4; ++r)
                    xv[r] = x[(size_t)(g * BM_ + quad * 4 + r) * T_ + t];
            }

            // ---- epilogue: relu(accA+accB+bias) -> lH[(t+1)&1] ----
#pragma unroll
            for (int nt = 0; nt < 2; ++nt) {
                const v4f aa = nt ? accA1 : accA0;
                const v4f ab = nt ? accB1 : accB0;
                const int n = nbase + nt * 16 + s16;
#pragma unroll
                for (int r = 0; r < 4; ++r) {
                    float v = aa[r] + ab[r] + bias[nt];
                    if (l == 0) v += xv[r] * w0v[nt];
                    v = fmaxf(v, 0.f);
                    lH[(t + 1) & 1][quad * 4 + r][n] = (_Float16)v;
                }
            }

            // ---- j3: unscramble pf[0..2] (bufX[0..2] dead: their steps passed;
            // j3 readers touch only bufX[3]); jj=3 carried to next j0 ----
            if (j == S_ - 1 && pfOK) {
#pragma unroll
                for (int jj = 0; jj < 3; ++jj) {
                    *(u64*)&bufX[jj][m_e][n_e]     = pfv[jj][0];
                    *(u64*)&bufX[jj][m_e][n_e + 4] = pfv[jj][1];
                }
                pfc0 = pfv[3][0];
                pfc1 = pfv[3][1];
            }
        }
    }

    if (l < L_ - 1) {
        // tail: export h(T-1) (in lH[0]), drain, publish all done
        u64 e0 = *(const u64*)&lH[0][m_e][n_e];
        u64 e1 = *(const u64*)&lH[0][m_e][n_e + 4];
        u64* d = myring + (size_t)(((T_ - 1) >> 2) & rmask) * RQWS_
                        + (size_t)3 * 1024 + eidx;
        __hip_atomic_store(d,     e0, __ATOMIC_RELAXED, __HIP_MEMORY_SCOPE_AGENT);
        __hip_atomic_store(d + 1, e1, __ATOMIC_RELAXED, __HIP_MEMORY_SCOPE_AGENT);
        __syncthreads();   // drains exports (vmcnt(0) before s_barrier)
        if (tid == 0)
            __hip_atomic_store(myprod, (unsigned)NS_, __ATOMIC_RELAXED,
                               __HIP_MEMORY_SCOPE_AGENT);
    } else {
        __syncthreads();
        // final FC: out[b] = h_T[b] @ W_fc^T + b_fc; h_T in lH[0]
        if (tid < BM_ * C_) {
            const int bl = tid / C_;
            const int c  = tid % C_;
            float sum = b_fc[c];
            for (int k = 0; k < H_; ++k) sum += (float)lH[0][bl][k] * W_fc[c * H_ + k];
            out[(size_t)(g * BM_ + bl) * C_ + c] = sum;
        }
    }
}

extern "C" void kernel_launch(void* const* d_in, const int* in_sizes, int n_in,
                              void* d_out, int out_size, void* d_ws, size_t ws_size,
                              hipStream_t stream) {
    const float* x     = (const float*)d_in[0];
    const float* W_ih0 = (const float*)d_in[1];
    const float* b_ih0 = (const float*)d_in[2];
    const float* W_ih  = (const float*)d_in[3];
    const float* b_ih  = (const float*)d_in[4];
    const float* W_hh  = (const float*)d_in[5];
    const float* b_hh  = (const float*)d_in[6];
    const float* W_fc  = (const float*)d_in[7];
    const float* b_fc  = (const float*)d_in[8];
    float* out = (float*)d_out;

    const size_t cntBytes = (size_t)L_ * G_ * sizeof(unsigned);   // 640 B each
    unsigned* prod = (unsigned*)d_ws;
    unsigned* cons = (unsigned*)((char*)d_ws + cntBytes);
    u64* ring      = (u64*)((char*)d_ws + 2 * cntBytes);

    // ring slots per link, by available workspace (32 KB per slot per link)
    const size_t slotBytes = (size_t)RQWS_ * 8;                   // 32 KB
    const size_t base = 2 * cntBytes;
    int R = 4;                                                    // 21 MB
    if (ws_size >= base + (size_t)L_ * G_ * 16 * slotBytes) R = 16;      // 84 MB
    else if (ws_size >= base + (size_t)L_ * G_ * 8 * slotBytes) R = 8;   // 42 MB

    hipMemsetAsync(d_ws, 0, 2 * cntBytes, stream);

    rnn_wavefront<<<dim3(L_ * G_), dim3(TPB_), 0, stream>>>(
        x, W_ih0, b_ih0, W_ih, b_ih, W_hh, b_hh, W_fc, b_fc,
        out, prod, cons, ring, R - 1);
}

// Round 9
// 1122.092 us; speedup vs baseline: 1.1233x; 1.1233x over previous
//
#include <hip/hip_runtime.h>
#include <hip/hip_fp16.h>

// Wavefront-pipelined 20-layer ReLU RNN for MI355X — round 9.
// Base = round 7 (best measured: 1148us) verbatim, ONE change: the X-half
// GEMM is hoisted out of the serial chain. At j0, XP[j] = X(4s+j)*W_ih^T +
// bias is computed for all 4 steps in one burst (8 indep chains of 8 MFMA,
// 256 back-to-back ds_read_b128/CU — streaming throughput, no serial-dep
// stalls), packed to fp16 (16 VGPRs; one extra rounding on the x-path only).
// Serial step shrinks to: barrier + 8 b128 h-reads + 16 MFMA + XP-add/relu +
// epilogue — the per-step LDS floor halves. r8's failed trims are NOT here.

#define B_    128
#define T_    784
#define H_    256
#define L_    20
#define C_    10
#define G_    8      // batch slices
#define BM_   16     // batch rows per block
#define S_    4      // timesteps per superstep / ring slot
#define NS_   196    // T_/S_
#define SW_   280    // LDS row stride in halves (140 dwords = 12 mod 32)
#define RQWS_ 4096   // u64 words per ring slot (4 x 16 x 256 halves = 32KB)
#define TPB_  512

typedef _Float16 v8h __attribute__((ext_vector_type(8)));
typedef _Float16 v4h __attribute__((ext_vector_type(4)));
typedef float    v4f __attribute__((ext_vector_type(4)));
typedef unsigned long long u64;

__global__ __launch_bounds__(TPB_, 1)
void rnn_wavefront(const float* __restrict__ x,
                   const float* __restrict__ W_ih0,
                   const float* __restrict__ b_ih0,
                   const float* __restrict__ W_ih,
                   const float* __restrict__ b_ih,
                   const float* __restrict__ W_hh,
                   const float* __restrict__ b_hh,
                   const float* __restrict__ W_fc,
                   const float* __restrict__ b_fc,
                   float* __restrict__ out,
                   unsigned* __restrict__ prod,    // [L_][G_] supersteps complete
                   unsigned* __restrict__ cons,    // [L_][G_] supersteps consumed
                   u64* __restrict__ ring,         // [L_][G_][R][RQWS_]
                   int rmask)                      // R-1, R power of two
{
    const int l    = blockIdx.x >> 3;
    const int g    = blockIdx.x & 7;
    const int tid  = threadIdx.x;
    const int lane = tid & 63;
    const int wave = tid >> 6;          // 0..7
    const int quad = lane >> 4;
    const int s16  = lane & 15;
    const int nbase = wave * 32;        // each wave owns 32 output columns
    const int m_e  = tid >> 5;          // export/pf row (0..15)
    const int n_e  = (tid & 31) * 8;    // export/pf col base (0..248)

    __shared__ __align__(16) _Float16 bufX[S_][BM_][SW_];  // staged input slot
    __shared__ __align__(16) _Float16 lH[2][BM_][SW_];     // own h, ping-pong

    for (int i = tid; i < 2 * BM_ * SW_; i += TPB_) (&lH[0][0][0])[i] = (_Float16)0.f;

    // ---- weight B-fragments: lane holds B[k=quad*8+i][n=lane&15] ----
    v8h wf[16][2];
#pragma unroll
    for (int kt = 0; kt < 16; ++kt) {
        const int k0 = kt * 32 + quad * 8;
#pragma unroll
        for (int nt = 0; nt < 2; ++nt) {
            const int j = nbase + nt * 16 + s16;
            v8h w;
            if (kt < 8) {
                if (l == 0) {
#pragma unroll
                    for (int i = 0; i < 8; ++i) w[i] = (_Float16)0.f;
                } else {
                    const float* src = &W_ih[(((size_t)(l - 1) * H_) + j) * H_ + k0];
#pragma unroll
                    for (int i = 0; i < 8; ++i) w[i] = (_Float16)src[i];
                }
            } else {
                const float* src = &W_hh[(((size_t)l * H_) + j) * H_ + (k0 - 256)];
#pragma unroll
                for (int i = 0; i < 8; ++i) w[i] = (_Float16)src[i];
            }
            wf[kt][nt] = w;
        }
    }

    float bias[2], w0v[2];
#pragma unroll
    for (int nt = 0; nt < 2; ++nt) {
        const int j = nbase + nt * 16 + s16;
        bias[nt] = b_hh[l * H_ + j] + ((l == 0) ? b_ih0[j] : b_ih[(l - 1) * H_ + j]);
        w0v[nt]  = (l == 0) ? W_ih0[j] : 0.f;
    }

    unsigned* upprod = prod + ((l > 0 ? l - 1 : 0) * G_ + g);
    unsigned* myprod = prod + (l * G_ + g);
    unsigned* mycons = cons + (l * G_ + g);
    unsigned* dncons = cons + (((l < L_ - 1) ? l + 1 : l) * G_ + g);
    const unsigned R = (unsigned)rmask + 1u;
    u64* myring = ring + ((size_t)(l * G_ + g) * (size_t)R) * RQWS_;
    u64* upring = ring + ((size_t)((l > 0 ? l - 1 : 0) * G_ + g) * (size_t)R) * RQWS_;

    unsigned pSeen = 0, cSeen = 0;         // tid64 / tid128 private
    const size_t eidx = (size_t)m_e * 64 + (size_t)(tid & 31) * 2;  // u64 idx in slot

    // ---- prologue (l>0): wait prod>=2, stage slot 0 into bufX (row-major) ----
    if (l > 0) {
        if (tid == 64) {
            while (pSeen < 2u) {
                pSeen = __hip_atomic_load(upprod, __ATOMIC_RELAXED,
                                          __HIP_MEMORY_SCOPE_AGENT);
                if (pSeen < 2u) __builtin_amdgcn_s_sleep(2);
            }
        }
        __syncthreads();
#pragma unroll
        for (int jj = 0; jj < S_; ++jj) {
            u64 v0 = __hip_atomic_load(upring + (size_t)jj * 1024 + eidx,
                                       __ATOMIC_RELAXED, __HIP_MEMORY_SCOPE_AGENT);
            u64 v1 = __hip_atomic_load(upring + (size_t)jj * 1024 + eidx + 1,
                                       __ATOMIC_RELAXED, __HIP_MEMORY_SCOPE_AGENT);
            *(u64*)&bufX[jj][m_e][n_e]     = v0;
            *(u64*)&bufX[jj][m_e][n_e + 4] = v1;
        }
    }

    for (int s = 0; s < NS_; ++s) {
        const bool pfOK = (l > 0) && (s + 1 < NS_);
        u64 pfv[S_][2];
        v4h XPh[S_][2];   // hoisted X-half results + bias, fp16 packed

#pragma unroll
        for (int j = 0; j < S_; ++j) {
            const int t = S_ * s + j;
            __syncthreads();   // step barrier (also drains vmem per compiler)

            if (j == 0) {
                if (tid == 0 && l > 0)
                    __hip_atomic_store(mycons, (unsigned)(s + 1), __ATOMIC_RELAXED,
                                       __HIP_MEMORY_SCOPE_AGENT); // slot s global free
                if (tid == 64 && pfOK) {            // guards pf of slot s+1 at j1
                    const unsigned tgt = (unsigned)(s + 2);
                    while (pSeen < tgt) {
                        pSeen = __hip_atomic_load(upprod, __ATOMIC_RELAXED,
                                                  __HIP_MEMORY_SCOPE_AGENT);
                        if (pSeen < tgt) __builtin_amdgcn_s_sleep(2);
                    }
                }
                if (tid == 128 && l < L_ - 1 && s >= (int)R) {  // guards exports into slot s
                    const unsigned tgt = (unsigned)(s - (int)R + 1);
                    while (cSeen < tgt) {
                        cSeen = __hip_atomic_load(dncons, __ATOMIC_RELAXED,
                                                  __HIP_MEMORY_SCOPE_AGENT);
                        if (cSeen < tgt) __builtin_amdgcn_s_sleep(2);
                    }
                }

                // ---- XP burst: XP[jj] = X(4s+jj)*W_ih^T + bias, all 4 steps.
                // 8 independent chains of 8 MFMA; 32 back-to-back b128 reads.
                if (l > 0) {
                    v4f xpa[S_][2];
#pragma unroll
                    for (int jj = 0; jj < S_; ++jj)
#pragma unroll
                        for (int nt = 0; nt < 2; ++nt)
                            xpa[jj][nt] = (v4f){bias[nt], bias[nt], bias[nt], bias[nt]};
#pragma unroll
                    for (int jj = 0; jj < S_; ++jj) {
#pragma unroll
                        for (int kt = 0; kt < 8; ++kt) {
                            v8h a = *(const v8h*)&bufX[jj][s16][kt * 32 + quad * 8];
                            xpa[jj][0] = __builtin_amdgcn_mfma_f32_16x16x32_f16(a, wf[kt][0], xpa[jj][0], 0, 0, 0);
                            xpa[jj][1] = __builtin_amdgcn_mfma_f32_16x16x32_f16(a, wf[kt][1], xpa[jj][1], 0, 0, 0);
                        }
                    }
#pragma unroll
                    for (int jj = 0; jj < S_; ++jj)
#pragma unroll
                        for (int nt = 0; nt < 2; ++nt)
#pragma unroll
                            for (int r = 0; r < 4; ++r)
                                XPh[jj][nt][r] = (_Float16)xpa[jj][nt][r];
                } else {
                    // layer 0: XP = bias + x*w0
#pragma unroll
                    for (int jj = 0; jj < S_; ++jj)
#pragma unroll
                        for (int r = 0; r < 4; ++r) {
                            float xv = x[(size_t)(g * BM_ + quad * 4 + r) * T_ + (S_ * s + jj)];
#pragma unroll
                            for (int nt = 0; nt < 2; ++nt)
                                XPh[jj][nt][r] = (_Float16)(bias[nt] + xv * w0v[nt]);
                        }
                }
            }

            if (j == 1) {
                if (tid == 0 && l < L_ - 1 && s >= 1)
                    __hip_atomic_store(myprod, (unsigned)s, __ATOMIC_RELAXED,
                                       __HIP_MEMORY_SCOPE_AGENT); // slots 0..s-1 done
                if (pfOK) {   // prefetch slot s+1 -> regs (used at j3)
                    const u64* base = upring + (size_t)((s + 1) & rmask) * RQWS_;
#pragma unroll
                    for (int jj = 0; jj < S_; ++jj) {
                        pfv[jj][0] = __hip_atomic_load(base + (size_t)jj * 1024 + eidx,
                                                       __ATOMIC_RELAXED,
                                                       __HIP_MEMORY_SCOPE_AGENT);
                        pfv[jj][1] = __hip_atomic_load(base + (size_t)jj * 1024 + eidx + 1,
                                                       __ATOMIC_RELAXED,
                                                       __HIP_MEMORY_SCOPE_AGENT);
                    }
                }
            }

            // ---- export h(t-1) (lag 1 step; lH[t&1] holds h(t-1)) ----
            if (l < L_ - 1 && t > 0) {
                u64 e0 = *(const u64*)&lH[t & 1][m_e][n_e];
                u64 e1 = *(const u64*)&lH[t & 1][m_e][n_e + 4];
                u64* d = myring + (size_t)(((t - 1) >> 2) & rmask) * RQWS_
                                + (size_t)((t - 1) & 3) * 1024 + eidx;
                __hip_atomic_store(d,     e0, __ATOMIC_RELAXED, __HIP_MEMORY_SCOPE_AGENT);
                __hip_atomic_store(d + 1, e1, __ATOMIC_RELAXED, __HIP_MEMORY_SCOPE_AGENT);
            }

            // ---- serial MFMA: h-half only (16 MFMA, 8 b128 reads) ----
            v4f acc0 = (v4f){0.f, 0.f, 0.f, 0.f};
            v4f acc1 = (v4f){0.f, 0.f, 0.f, 0.f};
#pragma unroll
            for (int kt = 8; kt < 16; ++kt) {
                v8h a = *(const v8h*)&lH[t & 1][s16][(kt - 8) * 32 + quad * 8];
                acc0 = __builtin_amdgcn_mfma_f32_16x16x32_f16(a, wf[kt][0], acc0, 0, 0, 0);
                acc1 = __builtin_amdgcn_mfma_f32_16x16x32_f16(a, wf[kt][1], acc1, 0, 0, 0);
            }

            // ---- epilogue: relu(XP[j] + acc) -> lH[(t+1)&1] ----
#pragma unroll
            for (int nt = 0; nt < 2; ++nt) {
                const v4f av = nt ? acc1 : acc0;
                const int n = nbase + nt * 16 + s16;
#pragma unroll
                for (int r = 0; r < 4; ++r) {
                    float v = (float)XPh[j][nt][r] + av[r];
                    v = fmaxf(v, 0.f);
                    lH[(t + 1) & 1][quad * 4 + r][n] = (_Float16)v;
                }
            }

            if (j == S_ - 1) {
                __syncthreads();   // all waves done with bufX of this superstep
                if (pfOK) {        // unscramble: pure ds_write_b64, no extraction
#pragma unroll
                    for (int jj = 0; jj < S_; ++jj) {
                        *(u64*)&bufX[jj][m_e][n_e]     = pfv[jj][0];
                        *(u64*)&bufX[jj][m_e][n_e + 4] = pfv[jj][1];
                    }
                }
            }
        }
    }

    if (l < L_ - 1) {
        // tail: export h(T-1) (in lH[0]: (783+1)&1), drain, publish all done
        u64 e0 = *(const u64*)&lH[0][m_e][n_e];
        u64 e1 = *(const u64*)&lH[0][m_e][n_e + 4];
        u64* d = myring + (size_t)(((T_ - 1) >> 2) & rmask) * RQWS_
                        + (size_t)3 * 1024 + eidx;
        __hip_atomic_store(d,     e0, __ATOMIC_RELAXED, __HIP_MEMORY_SCOPE_AGENT);
        __hip_atomic_store(d + 1, e1, __ATOMIC_RELAXED, __HIP_MEMORY_SCOPE_AGENT);
        __syncthreads();   // drains the exports (vmcnt(0) before s_barrier)
        if (tid == 0)
            __hip_atomic_store(myprod, (unsigned)NS_, __ATOMIC_RELAXED,
                               __HIP_MEMORY_SCOPE_AGENT);
    } else {
        __syncthreads();
        // final FC: out[b] = h_T[b] @ W_fc^T + b_fc; h_T in lH[0]
        if (tid < BM_ * C_) {
            const int bl = tid / C_;
            const int c  = tid % C_;
            float sum = b_fc[c];
            for (int k = 0; k < H_; ++k) sum += (float)lH[0][bl][k] * W_fc[c * H_ + k];
            out[(size_t)(g * BM_ + bl) * C_ + c] = sum;
        }
    }
}

extern "C" void kernel_launch(void* const* d_in, const int* in_sizes, int n_in,
                              void* d_out, int out_size, void* d_ws, size_t ws_size,
                              hipStream_t stream) {
    const float* x     = (const float*)d_in[0];
    const float* W_ih0 = (const float*)d_in[1];
    const float* b_ih0 = (const float*)d_in[2];
    const float* W_ih  = (const float*)d_in[3];
    const float* b_ih  = (const float*)d_in[4];
    const float* W_hh  = (const float*)d_in[5];
    const float* b_hh  = (const float*)d_in[6];
    const float* W_fc  = (const float*)d_in[7];
    const float* b_fc  = (const float*)d_in[8];
    float* out = (float*)d_out;

    const size_t cntBytes = (size_t)L_ * G_ * sizeof(unsigned);   // 640 B each
    unsigned* prod = (unsigned*)d_ws;
    unsigned* cons = (unsigned*)((char*)d_ws + cntBytes);
    u64* ring      = (u64*)((char*)d_ws + 2 * cntBytes);

    // ring slots per link, by available workspace (32 KB per slot per link)
    const size_t slotBytes = (size_t)RQWS_ * 8;                   // 32 KB
    const size_t base = 2 * cntBytes;
    int R = 4;                                                    // 21 MB
    if (ws_size >= base + (size_t)L_ * G_ * 16 * slotBytes) R = 16;      // 84 MB
    else if (ws_size >= base + (size_t)L_ * G_ * 8 * slotBytes) R = 8;   // 42 MB

    hipMemsetAsync(d_ws, 0, 2 * cntBytes, stream);

    rnn_wavefront<<<dim3(L_ * G_), dim3(TPB_), 0, stream>>>(
        x, W_ih0, b_ih0, W_ih, b_ih, W_hh, b_hh, W_fc, b_fc,
        out, prod, cons, ring, R - 1);
}